// Round 7
// baseline (262.760 us; speedup 1.0000x reference)
//
#include <hip/hip_runtime.h>
#include <math.h>

// Problem constants: N=100000, S=64, Q=50, P=3
#define N_Q 50
#define N_S 64
#define ROW 150            // floats per pauli word
#define HPAD 152           // padded H row (float4-aligned)
#define THREADS 256        // 4 waves per block
#define ROWS_PER_WAVE 32
#define ROWS_PER_BLOCK 128 // 4 waves x 32 rows
#define NWAVES 3128        // ceil(100000/32); grid = 782 blocks

// ws layout (bytes):
//   [0..4)        done-counter (memset to 0 each launch)
//   [64..25088)   partials double[NWAVES]
//   [25664..+38912) HPP float[64][152]  (per-s padded head rows, q-major inner)
//   [64640..+256)   hrv float[64]
#define WS_CNT_OFF 0
#define WS_PART_OFF 64
#define WS_HPP_OFF 25664
#define WS_HRV_OFF 64640

__device__ __forceinline__ float softplus20(float x) {
    float z = x * 20.0f;
    return fmaxf(z, 0.0f) + log1pf(expf(-fabsf(z)));  // stable softplus
}

__global__ void precompute_kernel(const float* __restrict__ heads_param,
                                  const float* __restrict__ hr_param,
                                  float* __restrict__ HPP,
                                  float* __restrict__ hrv) {
    const int tid = threadIdx.x;
    if (blockIdx.x == 0) {
        if (tid < N_S) {
            float sp = softplus20(hr_param[tid]);
            float tot = sp;
            #pragma unroll
            for (int off = 32; off; off >>= 1) tot += __shfl_xor(tot, off);
            hrv[tid] = (sp / fmaxf(tot, 1e-12f) + 0.001f / (float)N_S) / 1.001f;
        }
        if (tid < 2 * N_S)  // zero the 2-float pad of each H row
            HPP[(tid >> 1) * HPAD + 150 + (tid & 1)] = 0.0f;
    }
    // EXACT reference semantics: h_p = sp_p / max(sum, EPS). When the clamp
    // fires the row does NOT sum to 1 -> all three components stored.
    int idx = blockIdx.x * blockDim.x + tid;
    if (idx < N_S * N_Q) {
        int q = idx >> 6, s = idx & 63;
        const float* hp = heads_param + ((size_t)s * N_Q + q) * 3;
        float sp0 = softplus20(hp[0]);
        float sp1 = softplus20(hp[1]);
        float sp2 = softplus20(hp[2]);
        float denom = fmaxf(sp0 + sp1 + sp2, 1e-12f);
        float* o = HPP + (size_t)s * HPAD + q * 3;   // lane-s-private layout
        o[0] = sp0 / denom; o[1] = sp1 / denom; o[2] = sp2 / denom;
    }
}

// Lane = s. H is VGPR-resident per lane (no inner-loop H traffic).
// A is wave-uniform per row -> scalar-pipe s_load stream (touched once).
__global__ __launch_bounds__(THREADS, 3) void main_kernel(
    const float* __restrict__ A, const float* __restrict__ coeff,
    const float* __restrict__ HPP, const float* __restrict__ hrv,
    double* __restrict__ partials, int* __restrict__ cnt,
    float* __restrict__ out, int N) {
    __shared__ double redd[4];
    __shared__ int isLast;

    const int tid = threadIdx.x;
    const int lane = tid & 63;
    const int wv = tid >> 6;
    const int wave_id = blockIdx.x * 4 + wv;

    // --- load this lane's full H row into registers (once per wave) ---
    float h[HPAD];
    {
        const float4* Hv = (const float4*)(HPP + (size_t)lane * HPAD);
        #pragma unroll
        for (int j = 0; j < HPAD / 4; ++j) *(float4*)&h[4 * j] = Hv[j];
    }
    const float hrw = hrv[lane];

    const int rowbase = __builtin_amdgcn_readfirstlane(wave_id * ROWS_PER_WAVE);
    double dsum = 0.0;

    for (int it = 0; it < ROWS_PER_WAVE; ++it) {
        // force SGPR address -> compiler emits s_load for the A stream
        const int row = __builtin_amdgcn_readfirstlane(rowbase + it);
        if (row >= N) break;                       // wave-uniform guard
        const float* __restrict__ ar = A + (size_t)row * ROW;

        float prod = 1.0f;
        #pragma unroll
        for (int w = 0; w < 6; ++w) {              // 6 windows x 8 q
            float a[24];
            #pragma unroll
            for (int k = 0; k < 24; ++k) a[k] = ar[24 * w + k];  // uniform
            #pragma unroll
            for (int qq = 0; qq < 8; ++qq) {
                const int hb = 24 * w + 3 * qq;    // = 3*q, static
                float d = fmaf(h[hb + 0], a[3 * qq + 0],
                          fmaf(h[hb + 1], a[3 * qq + 1],
                               h[hb + 2] * a[3 * qq + 2]));
                prod *= d;
            }
        }
        {   // tail: q = 48, 49
            float a[6];
            #pragma unroll
            for (int k = 0; k < 6; ++k) a[k] = ar[144 + k];
            #pragma unroll
            for (int qq = 0; qq < 2; ++qq) {
                const int hb = 144 + 3 * qq;
                float d = fmaf(h[hb + 0], a[3 * qq + 0],
                          fmaf(h[hb + 1], a[3 * qq + 1],
                               h[hb + 2] * a[3 * qq + 2]));
                prod *= d;
            }
        }

        // cov[row] = sum_s hrv[s] * prod[s]  (register-only butterfly)
        float cv = prod * hrw;
        #pragma unroll
        for (int off = 32; off; off >>= 1) cv += __shfl_xor(cv, off);

        float c = coeff[row];                      // uniform scalar load
        dsum += (double)((c * c) / cv);
    }

    if (lane == 0) partials[wave_id] = dsum;       // all NWAVES slots written
    __syncthreads();

    if (tid == 0) {
        __threadfence();                           // release partials
        int v = atomicAdd(cnt, 1);
        isLast = (v == (int)gridDim.x - 1);
    }
    __syncthreads();

    if (isLast) {                                  // last block: final reduce
        __threadfence();                           // acquire
        double s = 0.0;
        for (int i = tid; i < NWAVES; i += THREADS) s += partials[i];
        #pragma unroll
        for (int off = 32; off; off >>= 1) s += __shfl_down(s, off);
        if (lane == 0) redd[wv] = s;
        __syncthreads();
        if (tid == 0) out[0] = (float)(redd[0] + redd[1] + redd[2] + redd[3]);
    }
}

extern "C" void kernel_launch(void* const* d_in, const int* in_sizes, int n_in,
                              void* d_out, int out_size, void* d_ws, size_t ws_size,
                              hipStream_t stream) {
    const float* A           = (const float*)d_in[0];  // [N, Q, P]
    const float* coeff       = (const float*)d_in[1];  // [N]
    const float* heads_param = (const float*)d_in[2];  // [S, Q, P]
    const float* hr_param    = (const float*)d_in[3];  // [S]
    const int N = in_sizes[1];

    char* ws = (char*)d_ws;
    int*    cnt      = (int*)(ws + WS_CNT_OFF);
    double* partials = (double*)(ws + WS_PART_OFF);
    float*  HPP      = (float*)(ws + WS_HPP_OFF);
    float*  hrv      = (float*)(ws + WS_HRV_OFF);
    float*  out      = (float*)d_out;

    hipMemsetAsync(cnt, 0, sizeof(int), stream);

    const int pre_blocks = (N_S * N_Q + THREADS - 1) / THREADS;  // 13
    precompute_kernel<<<pre_blocks, THREADS, 0, stream>>>(heads_param, hr_param,
                                                          HPP, hrv);
    const int nblocks = (N + ROWS_PER_BLOCK - 1) / ROWS_PER_BLOCK;  // 782
    main_kernel<<<nblocks, THREADS, 0, stream>>>(A, coeff, HPP, hrv,
                                                 partials, cnt, out, N);
}

// Round 8
// 210.485 us; speedup vs baseline: 1.2484x; 1.2484x over previous
//
#include <hip/hip_runtime.h>
#include <math.h>

// Problem constants: N=100000, S=64, Q=50, P=3
#define N_Q 50
#define N_S 64
#define ROW 150            // floats per pauli word
#define THREADS 256        // 4 waves per block
#define RPW 32             // rows per wave
#define RPB 128            // rows per block

// ws layout (bytes):
//   [0..4)          done-counter (memset 0 each launch)
//   [64..+8*nwaves) partials double[3128]
//   [25088..+38400) HT float[150][64]  transposed heads: HT[3q+p][s]
//   [63488..+256)   hrv float[64]
#define WS_CNT_OFF 0
#define WS_PART_OFF 64
#define WS_HT_OFF 25088
#define WS_HRV_OFF 63488

__device__ __forceinline__ float softplus20(float x) {
    float z = x * 20.0f;
    return fmaxf(z, 0.0f) + log1pf(expf(-fabsf(z)));  // stable softplus
}

__global__ void precompute_kernel(const float* __restrict__ heads_param,
                                  const float* __restrict__ hr_param,
                                  float* __restrict__ HT,
                                  float* __restrict__ hrv) {
    const int tid = threadIdx.x;
    if (blockIdx.x == 0 && tid < N_S) {
        float sp = softplus20(hr_param[tid]);
        float tot = sp;
        #pragma unroll
        for (int off = 32; off; off >>= 1) tot += __shfl_xor(tot, off);
        hrv[tid] = (sp / fmaxf(tot, 1e-12f) + 0.001f / (float)N_S) / 1.001f;
    }
    // EXACT reference semantics: h_p = sp_p / max(sum, EPS). When the clamp
    // fires the row does NOT sum to 1 -> all three components stored.
    int idx = blockIdx.x * blockDim.x + tid;
    if (idx < N_S * N_Q) {
        int q = idx >> 6, s = idx & 63;
        const float* hp = heads_param + ((size_t)s * N_Q + q) * 3;
        float sp0 = softplus20(hp[0]);
        float sp1 = softplus20(hp[1]);
        float sp2 = softplus20(hp[2]);
        float denom = fmaxf(sp0 + sp1 + sp2, 1e-12f);
        // transposed: HT[k][s], k = 3q+p  -> lane=s reads are coalesced
        HT[(3 * q + 0) * N_S + s] = sp0 / denom;
        HT[(3 * q + 1) * N_S + s] = sp1 / denom;
        HT[(3 * q + 2) * N_S + s] = sp2 / denom;
    }
}

// 8 qubits of one row against this lane's s: hv = 24 VGPR-resident H floats,
// ar = wave-uniform A slice (scalar-pipe s_loads, 1 SGPR per fma operand).
__device__ __forceinline__ void bodyQ8(const float* __restrict__ ar,
                                       const float (&hv)[24], float& p) {
    #pragma unroll
    for (int qq = 0; qq < 8; ++qq)
        p *= fmaf(hv[3 * qq + 0], ar[3 * qq + 0],
             fmaf(hv[3 * qq + 1], ar[3 * qq + 1],
                  hv[3 * qq + 2] * ar[3 * qq + 2]));
}

__global__ __launch_bounds__(THREADS) void main_kernel(
    const float* __restrict__ A, const float* __restrict__ coeff,
    const float* __restrict__ HT, const float* __restrict__ hrv,
    double* __restrict__ partials, int* __restrict__ cnt,
    float* __restrict__ out, int N, int nwaves_tot) {
    __shared__ double redd[4];
    __shared__ int isLast;

    const int tid = threadIdx.x;
    const int lane = tid & 63;
    const int wv = __builtin_amdgcn_readfirstlane(tid >> 6);
    const int wave_id = blockIdx.x * 4 + wv;          // uniform
    const int rowbase = wave_id * RPW;                // uniform

    double dsum = 0.0;
    if (rowbase < N) {
        const float hrw = hrv[lane];                  // coalesced, once

        float prod[RPW];
        #pragma unroll
        for (int r = 0; r < RPW; ++r) prod[r] = 1.0f;

        // ---- 6 full windows of 8 q ----
        for (int w = 0; w < 6; ++w) {
            float hv[24];                             // VGPRs, vmcnt domain
            #pragma unroll
            for (int j = 0; j < 24; ++j) hv[j] = HT[(24 * w + j) * N_S + lane];

            #pragma unroll
            for (int r = 0; r < RPW; r += 2) {        // 2 rows per lgkm drain
                int r0 = rowbase + r;     if (r0 >= N) r0 = N - 1;
                int r1 = rowbase + r + 1; if (r1 >= N) r1 = N - 1;
                const float* ar0 = A + (size_t)r0 * ROW + 24 * w;  // uniform
                const float* ar1 = A + (size_t)r1 * ROW + 24 * w;
                bodyQ8(ar0, hv, prod[r]);
                bodyQ8(ar1, hv, prod[r + 1]);
            }
        }
        // ---- tail window: q = 48,49 (k = 144..149) ----
        {
            float hv6[6];
            #pragma unroll
            for (int j = 0; j < 6; ++j) hv6[j] = HT[(144 + j) * N_S + lane];
            #pragma unroll
            for (int r = 0; r < RPW; ++r) {
                int rr = rowbase + r; if (rr >= N) rr = N - 1;
                const float* ar = A + (size_t)rr * ROW + 144;
                float d0 = fmaf(hv6[0], ar[0], fmaf(hv6[1], ar[1], hv6[2] * ar[2]));
                float d1 = fmaf(hv6[3], ar[3], fmaf(hv6[4], ar[4], hv6[5] * ar[5]));
                prod[r] *= d0 * d1;
            }
        }

        // ---- epilogue: per-row butterfly over s, uniform accumulate ----
        #pragma unroll
        for (int r = 0; r < RPW; ++r) {
            float cv = prod[r] * hrw;
            #pragma unroll
            for (int off = 32; off; off >>= 1) cv += __shfl_xor(cv, off);
            if (rowbase + r < N) {
                float c = coeff[rowbase + r];         // uniform s_load
                dsum += (double)((c * c) / cv);       // same value in all lanes
            }
        }
    }
    if (lane == 0) partials[wave_id] = dsum;
    __syncthreads();

    if (tid == 0) {
        __threadfence();                              // release partials
        int v = atomicAdd(cnt, 1);
        isLast = (v == (int)gridDim.x - 1);
    }
    __syncthreads();

    if (isLast) {                                     // last block: final sum
        __threadfence();                              // acquire
        double s = 0.0;
        for (int i = tid; i < nwaves_tot; i += THREADS) s += partials[i];
        #pragma unroll
        for (int off = 32; off; off >>= 1) s += __shfl_down(s, off);
        if (lane == 0) redd[tid >> 6] = s;
        __syncthreads();
        if (tid == 0) out[0] = (float)(redd[0] + redd[1] + redd[2] + redd[3]);
    }
}

extern "C" void kernel_launch(void* const* d_in, const int* in_sizes, int n_in,
                              void* d_out, int out_size, void* d_ws, size_t ws_size,
                              hipStream_t stream) {
    const float* A           = (const float*)d_in[0];  // [N, Q, P]
    const float* coeff       = (const float*)d_in[1];  // [N]
    const float* heads_param = (const float*)d_in[2];  // [S, Q, P]
    const float* hr_param    = (const float*)d_in[3];  // [S]
    const int N = in_sizes[1];

    char* ws = (char*)d_ws;
    int*    cnt      = (int*)(ws + WS_CNT_OFF);
    double* partials = (double*)(ws + WS_PART_OFF);
    float*  HT       = (float*)(ws + WS_HT_OFF);
    float*  hrv      = (float*)(ws + WS_HRV_OFF);
    float*  out      = (float*)d_out;

    hipMemsetAsync(cnt, 0, sizeof(int), stream);

    const int pre_blocks = (N_S * N_Q + THREADS - 1) / THREADS;  // 13
    precompute_kernel<<<pre_blocks, THREADS, 0, stream>>>(heads_param, hr_param,
                                                          HT, hrv);
    const int nblocks = (N + RPB - 1) / RPB;          // 782
    const int nwaves_tot = nblocks * 4;               // 3128
    main_kernel<<<nblocks, THREADS, 0, stream>>>(A, coeff, HT, hrv,
                                                 partials, cnt, out, N,
                                                 nwaves_tot);
}